// Round 11
// baseline (184.895 us; speedup 1.0000x reference)
//
#include <hip/hip_runtime.h>
#include <stdint.h>
#include <stddef.h>

#define DMODEL 768
#define NHEAD 12
#define SEQLEN 2048
#define NBATCH 2
#define DH 64
#define MTOT (NBATCH*SEQLEN)   // 4096

typedef short s16x4 __attribute__((ext_vector_type(4)));
typedef short s16x8 __attribute__((ext_vector_type(8)));
typedef float f32x4 __attribute__((ext_vector_type(4)));

// ws layout (bf16 element offsets)
#define XDECB_OFF 0u
#define XENCB_OFF 3145728u
#define WQB_OFF   6291456u
#define WKB_OFF   6881280u
#define WVB_OFF   7471104u
#define WOUTB_OFF 8060928u
#define QB_OFF    8650752u
#define KB_OFF    11796480u
#define VT_OFF    14942208u
#define CTXB_OFF  18087936u
// After qkv_gemm, the xDecB/xEncB/wQB regions are dead -> reuse as fp32
// partial-attention buffers (exact fit: 24*1024*64 f32 = 6291456 B each).
//   POUT0 = ws+XDECB_OFF  : blockB partial O   [bh][q-1024][64] f32
//   POUT1 = ws+XENCB_OFF  : blockA ph2 partial [bh][q-1024][64] f32
//   LPART = ws+WQB_OFF    : [2][bh*1024+q-1024] f32 row sums
// R18: norm_kernel deleted — out_gemm combines the partials for upper-half
// rows during its A-staging. Sync comes from the attn->out kernel boundary
// (stream order), NOT in-kernel atomics (R10's handshake raced — reverted).

// 0.125 * log2(e): folds the 1/sqrt(Dh) scale and exp->exp2 into Q epilogue.
#define QSCALE 0.18033688011112042f

// fp32 -> bf16, round-to-nearest-even (epilogues)
static __device__ __forceinline__ unsigned short f2bf(float f) {
  union { float f; unsigned int u; } v; v.f = f;
  unsigned int r = v.u + 0x7fffu + ((v.u >> 16) & 1u);
  return (unsigned short)(r >> 16);
}

// pack two fp32 -> bf16x2 with round-half-up: 2 adds + 1 v_perm
static __device__ __forceinline__ unsigned int pack2bf(float f0, float f1) {
  union { float f; unsigned int u; } a, b; a.f = f0; b.f = f1;
  return __builtin_amdgcn_perm(b.u + 0x8000u, a.u + 0x8000u, 0x07060302u);
}

#if __has_builtin(__builtin_amdgcn_exp2f)
#define EXP2(x) __builtin_amdgcn_exp2f(x)
#else
#define EXP2(x) exp2f(x)
#endif

static __device__ __forceinline__ f32x4 mfma16(s16x4 a, s16x4 b, f32x4 c) {
  return __builtin_amdgcn_mfma_f32_16x16x16bf16_1k(a, b, c, 0, 0, 0);
}
static __device__ __forceinline__ f32x4 mfma32(s16x8 a, s16x8 b, f32x4 c) {
  return __builtin_amdgcn_mfma_f32_16x16x32_bf16(a, b, c, 0, 0, 0);
}

// async global->LDS DMA, 16B/lane. LDS dest = wave-uniform base + lane*16.
typedef __attribute__((address_space(3))) unsigned int lds_u32_t;
typedef const __attribute__((address_space(1))) unsigned int glb_u32_t;
static __device__ __forceinline__ void gl_lds16(const unsigned short* g,
                                                unsigned short* l) {
  __builtin_amdgcn_global_load_lds((glb_u32_t*)g, (lds_u32_t*)l, 16, 0, 0);
}

// ---------------------------------------------------------------------------
// One-time fp32 -> bf16 convert of all GEMM operands. Memory-bound (~45 MB).
// ---------------------------------------------------------------------------
__global__ __launch_bounds__(256) void cvt_kernel(
    const float* __restrict__ xDec, const float* __restrict__ xEnc,
    const float* __restrict__ wQ, const float* __restrict__ wK,
    const float* __restrict__ wV, const float* __restrict__ wOut,
    unsigned short* __restrict__ ws)
{
  const int seg = blockIdx.y;
  const float* src;
  unsigned int n4, off;
  switch (seg) {
    case 0:  src = xDec; n4 = 786432; off = XDECB_OFF; break;
    case 1:  src = xEnc; n4 = 786432; off = XENCB_OFF; break;
    case 2:  src = wQ;   n4 = 147456; off = WQB_OFF;   break;
    case 3:  src = wK;   n4 = 147456; off = WKB_OFF;   break;
    case 4:  src = wV;   n4 = 147456; off = WVB_OFF;   break;
    default: src = wOut; n4 = 147456; off = WOUTB_OFF; break;
  }
  unsigned short* d = ws + off;
  const unsigned int stride = gridDim.x * blockDim.x;
  for (unsigned int i = blockIdx.x * blockDim.x + threadIdx.x; i < n4; i += stride) {
    const float4 v = ((const float4*)src)[i];
    s16x4 p;
    p[0] = (short)f2bf(v.x); p[1] = (short)f2bf(v.y);
    p[2] = (short)f2bf(v.z); p[3] = (short)f2bf(v.w);
    ((s16x4*)d)[i] = p;
  }
}

// ---------------------------------------------------------------------------
// bf16 NT GEMM, 64x64 tile, BK=64, 16x16x32 MFMA, gl_lds16 + XOR chunk
// swizzle. Counted-vmcnt 3-buffer pipeline (T4, R3-verified best).
// ---------------------------------------------------------------------------
#define BK 64
#define NKT (DMODEL / BK)   // 12

// QKV: z=0 Q=xDecB@wQ.T (+bQ)*QSCALE -> Qb[b,h,s,d]; z=1 K -> Kb; z=2 V -> Vt[b,h,d,s]
__global__ __launch_bounds__(256, 3) void qkv_gemm(
    const unsigned short* __restrict__ xDecB, const unsigned short* __restrict__ xEncB,
    const unsigned short* __restrict__ wQB, const unsigned short* __restrict__ wKB,
    const unsigned short* __restrict__ wVB,
    const float* __restrict__ bQ, const float* __restrict__ bK, const float* __restrict__ bV,
    unsigned short* __restrict__ Qb, unsigned short* __restrict__ Kb,
    unsigned short* __restrict__ Vt)
{
  const int z = blockIdx.z;
  const unsigned short* __restrict__ A = (z == 0) ? xDecB : xEncB;
  const unsigned short* __restrict__ B = (z == 0) ? wQB : ((z == 1) ? wKB : wVB);
  const float* __restrict__ bias = (z == 0) ? bQ : ((z == 1) ? bK : bV);

  __shared__ unsigned short lA[3][64 * BK];   // 3 x 8 KB, swizzled chunks
  __shared__ unsigned short lB[3][64 * BK];

  const int tid  = threadIdx.x;
  const int lane = tid & 63;
  const int wid  = tid >> 6;
  const int ln   = lane & 15;
  const int qd   = lane >> 4;
  const int m0 = blockIdx.x * 64;
  const int n0 = blockIdx.y * 64;
  const int wm = (wid & 1) * 32;
  const int wn = (wid >> 1) * 32;

  // staging: slot s = c*256 + wid*64 + lane (16B chunks); row = s>>3,
  // stored chunk = s&7, source chunk = (s&7) ^ (row&7).
  int srow[2], scol[2];
  #pragma unroll
  for (int c = 0; c < 2; ++c) {
    const int s = c * 256 + wid * 64 + lane;
    srow[c] = s >> 3;
    scol[c] = (((s & 7) ^ ((s >> 3) & 7)) * 8);
  }

  auto stage = [&](int buf, int k0) {
    #pragma unroll
    for (int c = 0; c < 2; ++c) {
      const int ldsoff = (c * 256 + wid * 64) * 8;     // shorts
      gl_lds16(A + (size_t)(m0 + srow[c]) * DMODEL + k0 + scol[c], &lA[buf][ldsoff]);
      gl_lds16(B + (size_t)(n0 + srow[c]) * DMODEL + k0 + scol[c], &lB[buf][ldsoff]);
    }
  };

  f32x4 acc[2][2] = {};

  stage(0, 0);
  stage(1, BK);            // 8 loads/lane in flight

  auto step = [&](int t, int bc, int bs) {
    if (t == NKT - 1) asm volatile("s_waitcnt vmcnt(0)" ::: "memory");
    else              asm volatile("s_waitcnt vmcnt(4)" ::: "memory");
    __builtin_amdgcn_s_barrier();
    __builtin_amdgcn_sched_barrier(0);
    if (t + 2 < NKT) stage(bs, (t + 2) * BK);
    #pragma unroll
    for (int kc = 0; kc < 2; ++kc) {
      s16x8 af[2], bfr[2];
      #pragma unroll
      for (int i = 0; i < 2; ++i) {
        const int r = wm + i * 16 + ln;
        af[i] = *(const s16x8*)&lA[bc][r * 64 + (((kc * 4 + qd) ^ (r & 7)) * 8)];
      }
      #pragma unroll
      for (int j = 0; j < 2; ++j) {
        const int r = wn + j * 16 + ln;
        bfr[j] = *(const s16x8*)&lB[bc][r * 64 + (((kc * 4 + qd) ^ (r & 7)) * 8)];
      }
      #pragma unroll
      for (int i = 0; i < 2; ++i)
        #pragma unroll
        for (int j = 0; j < 2; ++j)
          acc[i][j] = mfma32(af[i], bfr[j], acc[i][j]);
    }
  };

  for (int tb = 0; tb < NKT; tb += 3) {   // NKT % 3 == 0: bufs fold statically
    step(tb + 0, 0, 2);
    step(tb + 1, 1, 0);
    step(tb + 2, 2, 1);
  }

  // C/D layout: col = ln, row = qd*4 + r
  #pragma unroll
  for (int j = 0; j < 2; ++j) {
    const int n_g = n0 + wn + j * 16 + ln;
    const float bv = bias[n_g];
    const int h    = n_g >> 6;
    const int dcol = n_g & 63;
    #pragma unroll
    for (int i = 0; i < 2; ++i) {
      #pragma unroll
      for (int r = 0; r < 4; ++r) {
        const int m_g  = m0 + wm + i * 16 + qd * 4 + r;
        const int bb   = m_g >> 11;
        const int srow2 = m_g & 2047;
        const float val = acc[i][j][r] + bv;
        if (z == 0)
          Qb[((size_t)((bb * NHEAD + h) * SEQLEN + srow2)) * DH + dcol] = f2bf(val * QSCALE);
        else if (z == 1)
          Kb[((size_t)((bb * NHEAD + h) * SEQLEN + srow2)) * DH + dcol] = f2bf(val);
        else
          Vt[((size_t)((bb * NHEAD + h) * DH + dcol)) * SEQLEN + srow2] = f2bf(val);
      }
    }
  }
}

// ---------------------------------------------------------------------------
// out GEMM + FUSED PARTIAL COMBINE (R18). Lower-half m-tiles (ctx rows
// s<1024, fully written by attn mode-0) keep the counted-vmcnt DMA pipeline.
// Upper-half m-tiles (s>=1024) stage A by reading pout0+pout1 fp32, scaling
// by 1/(l0+l1), f2bf (EXACTLY norm_kernel's expression), and ds_write into
// the identical swizzled LDS slot the DMA would fill. k-tile head = k0>>6
// (64-aligned k never straddles heads). Upper blocks use a plain dbuf
// __syncthreads schedule (reg-staging can't share the vmcnt accounting).
// Sync with attn = kernel boundary: race-free by construction.
// ---------------------------------------------------------------------------
__global__ __launch_bounds__(256, 3) void out_gemm(
    const unsigned short* __restrict__ ctx, const unsigned short* __restrict__ wOutB,
    const float* __restrict__ bOut, float* __restrict__ out,
    const float* __restrict__ pout0, const float* __restrict__ pout1,
    const float* __restrict__ lpart)
{
  __shared__ unsigned short lA[3][64 * BK];
  __shared__ unsigned short lB[3][64 * BK];

  const int tid  = threadIdx.x;
  const int lane = tid & 63;
  const int wid  = tid >> 6;
  const int ln   = lane & 15;
  const int qd   = lane >> 4;
  const int m0 = blockIdx.x * 64;
  const int n0 = blockIdx.y * 64;
  const int wm = (wid & 1) * 32;
  const int wn = (wid >> 1) * 32;
  const bool up = (m0 & 1024) != 0;   // tile rows have s >= 1024

  int srow[2], scol[2];
  #pragma unroll
  for (int c = 0; c < 2; ++c) {
    const int s = c * 256 + wid * 64 + lane;
    srow[c] = s >> 3;
    scol[c] = (((s & 7) ^ ((s >> 3) & 7)) * 8);
  }

  auto stageB = [&](int buf, int k0) {
    #pragma unroll
    for (int c = 0; c < 2; ++c) {
      const int ldsoff = (c * 256 + wid * 64) * 8;
      gl_lds16(wOutB + (size_t)(n0 + srow[c]) * DMODEL + k0 + scol[c], &lB[buf][ldsoff]);
    }
  };
  auto stageA = [&](int buf, int k0) {
    #pragma unroll
    for (int c = 0; c < 2; ++c) {
      const int ldsoff = (c * 256 + wid * 64) * 8;
      gl_lds16(ctx + (size_t)(m0 + srow[c]) * DMODEL + k0 + scol[c], &lA[buf][ldsoff]);
    }
  };

  f32x4 acc[2][2] = {};

  auto compute = [&](int bc) {
    #pragma unroll
    for (int kc = 0; kc < 2; ++kc) {
      s16x8 af[2], bfr[2];
      #pragma unroll
      for (int i = 0; i < 2; ++i) {
        const int r = wm + i * 16 + ln;
        af[i] = *(const s16x8*)&lA[bc][r * 64 + (((kc * 4 + qd) ^ (r & 7)) * 8)];
      }
      #pragma unroll
      for (int j = 0; j < 2; ++j) {
        const int r = wn + j * 16 + ln;
        bfr[j] = *(const s16x8*)&lB[bc][r * 64 + (((kc * 4 + qd) ^ (r & 7)) * 8)];
      }
      #pragma unroll
      for (int i = 0; i < 2; ++i)
        #pragma unroll
        for (int j = 0; j < 2; ++j)
          acc[i][j] = mfma32(af[i], bfr[j], acc[i][j]);
    }
  };

  if (!up) {
    // ---- counted-vmcnt 3-buffer pipeline (R9-identical) ----
    stageA(0, 0); stageB(0, 0);
    stageA(1, BK); stageB(1, BK);
    auto step = [&](int t, int bc, int bs) {
      if (t == NKT - 1) asm volatile("s_waitcnt vmcnt(0)" ::: "memory");
      else              asm volatile("s_waitcnt vmcnt(4)" ::: "memory");
      __builtin_amdgcn_s_barrier();
      __builtin_amdgcn_sched_barrier(0);
      if (t + 2 < NKT) { stageA(bs, (t + 2) * BK); stageB(bs, (t + 2) * BK); }
      compute(bc);
    };
    for (int tb = 0; tb < NKT; tb += 3) {
      step(tb + 0, 0, 2);
      step(tb + 1, 1, 0);
      step(tb + 2, 2, 1);
    }
    __syncthreads();   // keep epilogue timing uniform (cheap)
  } else {
    // ---- fused combine path: A from pout0+pout1, plain dbuf schedule ----
    int rbase[2];   // b*12*1024 + (s - 1024): pout row base without head term
    #pragma unroll
    for (int c = 0; c < 2; ++c) {
      const int r_g = m0 + srow[c];
      rbase[c] = (r_g >> 11) * (NHEAD * 1024) + ((r_g & 2047) - 1024);
    }
    auto stageA_up = [&](int buf, int k0) {
      const int h = k0 >> 6;
      #pragma unroll
      for (int c = 0; c < 2; ++c) {
        const int s    = c * 256 + wid * 64 + lane;
        const int rowp = rbase[c] + h * 1024;        // bh*1024 + q'
        const int f4   = rowp * 16 + (scol[c] >> 2);
        const float4 a0 = ((const float4*)pout0)[f4];
        const float4 a1 = ((const float4*)pout0)[f4 + 1];
        const float4 c0 = ((const float4*)pout1)[f4];
        const float4 c1 = ((const float4*)pout1)[f4 + 1];
        const float inv = 1.0f / (lpart[rowp] + lpart[24 * 1024 + rowp]);
        union { unsigned short us[8]; s16x8 v; } pk;
        pk.us[0] = f2bf((a0.x + c0.x) * inv);
        pk.us[1] = f2bf((a0.y + c0.y) * inv);
        pk.us[2] = f2bf((a0.z + c0.z) * inv);
        pk.us[3] = f2bf((a0.w + c0.w) * inv);
        pk.us[4] = f2bf((a1.x + c1.x) * inv);
        pk.us[5] = f2bf((a1.y + c1.y) * inv);
        pk.us[6] = f2bf((a1.z + c1.z) * inv);
        pk.us[7] = f2bf((a1.w + c1.w) * inv);
        *(s16x8*)&lA[buf][s * 8] = pk.v;
      }
    };

    stageA_up(0, 0); stageB(0, 0);
    __syncthreads();
    int cur = 0;
    for (int t = 0; t < NKT; ++t) {
      if (t + 1 < NKT) { stageB(cur ^ 1, (t + 1) * BK); stageA_up(cur ^ 1, (t + 1) * BK); }
      compute(cur);
      __syncthreads();   // drains B DMA (vmcnt) + lA ds_writes (lgkm)
      cur ^= 1;
    }
  }

  #pragma unroll
  for (int j = 0; j < 2; ++j) {
    const int n_g = n0 + wn + j * 16 + ln;
    const float bv = bOut[n_g];
    #pragma unroll
    for (int i = 0; i < 2; ++i) {
      #pragma unroll
      for (int r = 0; r < 4; ++r) {
        const int m_g = m0 + wm + i * 16 + qd * 4 + r;
        out[(size_t)m_g * DMODEL + n_g] = acc[i][j][r] + bv;
      }
    }
  }
}

// ---------------------------------------------------------------------------
// Flash attention, FIXED-BASE softmax — R16 pipeline (counted-vmcnt 3-buffer,
// KVT=64, 3 blocks/CU), R9-passing version (no in-kernel handshake).
// ---------------------------------------------------------------------------
#define KVT 64
#define VOFF 4096   // shorts: V tile offset inside one buffer
#define RST 68      // epilogue fp32 row stride (64+4)

__global__ __launch_bounds__(256, 3) void attn_kernel(
    const unsigned short* __restrict__ Qb, const unsigned short* __restrict__ Kb,
    const unsigned short* __restrict__ Vt, unsigned short* __restrict__ ctx,
    float* __restrict__ pout0, float* __restrict__ pout1,
    float* __restrict__ lpart)
{
  // [buf][ lK 4096 shorts | lV 4096 shorts ] = 3 x 16 KB = 48 KB
  __shared__ __attribute__((aligned(16))) unsigned short smem[3][8192];

  const int tid  = threadIdx.x;
  const int lane = tid & 63;
  const int wid  = tid >> 6;
  const int ln   = lane & 15;
  const int qd   = lane >> 4;
  const int qw   = wid & 1;    // q-half owner
  const int kw   = wid >> 1;   // kv-strip owner (32 rows)

  // XCD-local remap: all blocks of a head on one XCD (L2-resident KV)
  const int ord  = blockIdx.x;          // 0..767
  const int xcd  = ord & 7;
  const int slot = ord >> 3;            // 0..95
  const int bh   = xcd * 3 + (slot >> 5);
  const int p    = slot & 31;           // 0..31

  const bool isA = p < 16;
  const int i  = isA ? p : (p - 16);    // pair index 0..15
  const int Ti = (i + 2) >> 1;          // ceil((i+1)/2): KVT128-units of qtile i

  const unsigned short* Kbase = Kb + (size_t)bh * SEQLEN * DH;
  const unsigned short* Vbase = Vt + (size_t)bh * DH * SEQLEN;
  const int bb = bh / NHEAD;
  const int h  = bh % NHEAD;

  float* rO = (float*)&smem[0][0];      // 64 x RST f32 (aliases buf0+buf1)
  float* rL = rO + 64 * RST;

  // DMA stage (4 loads/lane): K tile [64][64], V tile [64][64]; chunk f:
  // row=f>>3, slot=f&7, stored content = source chunk slot^(row&7).
  auto stage = [&](int b, int kv0) {
    #pragma unroll
    for (int c = 0; c < 2; ++c) {
      const int f = tid + c * 256;   // 0..511
      const int row = f >> 3, sl = f & 7;
      gl_lds16(Kbase + (size_t)(kv0 + row) * DH + ((sl ^ (row & 7)) * 8),
               &smem[b][f * 8]);
    }
    #pragma unroll
    for (int c = 0; c < 2; ++c) {
      const int f = tid + c * 256;
      const int row = f >> 3, sl = f & 7;
      gl_lds16(Vbase + (size_t)row * SEQLEN + kv0 + ((sl ^ (row & 7)) * 8),
               &smem[b][VOFF + f * 8]);
    }
  };

  // mode 0: final (normalize + bf16 ctx write); 1: partial->slot1; 2: ->slot0
  // T0/NT in KVT128 units (kv range [T0*128, (T0+NT)*128)).
  auto run = [&](int q0, int T0, int NT, int mode) {
    const int t0 = T0 * 2, tend = (T0 + NT) * 2;   // KVT64 tiles; tend-t0 >= 2

    // Q fragments: this wave's 32 q rows (B-operand layout)
    s16x8 Qf[2][2];
    #pragma unroll
    for (int qc = 0; qc < 2; ++qc)
      #pragma unroll
      for (int kc = 0; kc < 2; ++kc)
        Qf[qc][kc] = *(const s16x8*)(Qb +
            ((size_t)bh * SEQLEN + q0 + qw * 32 + qc * 16 + ln) * DH + kc * 32 + qd * 8);

    float l_acc[2] = {};
    f32x4 acc[2][4] = {};   // [qc][dc]: O[q0+qw*32+qc*16+qd*4+r][dc*16+ln]

    stage(0, t0 * KVT);
    stage(1, (t0 + 1) * KVT);
    int bc = 0;
    for (int t = t0; t < tend; ++t) {
      if (t + 1 < tend) asm volatile("s_waitcnt vmcnt(4)" ::: "memory");
      else              asm volatile("s_waitcnt vmcnt(0)" ::: "memory");
      __builtin_amdgcn_s_barrier();
      __builtin_amdgcn_sched_barrier(0);
      if (t + 2 < tend) stage(bc >= 1 ? bc - 1 : bc + 2, (t + 2) * KVT);

      const unsigned short* lK = &smem[bc][0];
      const unsigned short* lV = &smem[bc][VOFF];
      const int kv0 = t * KVT;
      const bool diag = (kv0 + KVT > q0);   // 64-aligned ranges: one diag tile

      // S^T strips: kv = kv0 + kw*32 + t8*16 + qd*4 + r, q = q0+qw*32+qc*16+ln
      s16x4 pf[2][2];
      #pragma unroll
      for (int t8 = 0; t8 < 2; ++t8) {
        const int row = kw * 32 + t8 * 16 + ln;      // row&7 == ln&7
        const s16x8 k0 = *(const s16x8*)&lK[row * 64 + ((qd ^ (ln & 7)) * 8)];
        const s16x8 k1 = *(const s16x8*)&lK[row * 64 + (((4 + qd) ^ (ln & 7)) * 8)];
        f32x4 sq[2] = {};
        sq[0] = mfma32(k0, Qf[0][0], sq[0]);
        sq[0] = mfma32(k1, Qf[0][1], sq[0]);
        sq[1] = mfma32(k0, Qf[1][0], sq[1]);
        sq[1] = mfma32(k1, Qf[1][1], sq[1]);
        #pragma unroll
        for (int qc = 0; qc < 2; ++qc) {
          if (diag) {
            #pragma unroll
            for (int r = 0; r < 4; ++r) {
              const int kv = kv0 + kw * 32 + t8 * 16 + qd * 4 + r;
              const int q  = q0 + qw * 32 + qc * 16 + ln;
              sq[qc][r] = (kv > q) ? -1e30f : sq[qc][r];
            }
          }
          const float p0 = EXP2(sq[qc][0]);
          const float p1 = EXP2(sq[qc][1]);
          const float p2 = EXP2(sq[qc][2]);
          const float p3 = EXP2(sq[qc][3]);
          l_acc[qc] += (p0 + p1) + (p2 + p3);
          union { unsigned int u[2]; s16x4 v; } pk;
          pk.u[0] = pack2bf(p0, p1);
          pk.u[1] = pack2bf(p2, p3);
          pf[t8][qc] = pk.v;
        }
      }

      // O += P @ V over this wave's 32-kv strip
      #pragma unroll
      for (int t8 = 0; t8 < 2; ++t8) {
        #pragma unroll
        for (int dc = 0; dc < 4; ++dc) {
          const int vrow  = dc * 16 + ln;            // row&7 == ln&7
          const int slotv = (kw * 4 + t8 * 2 + (qd >> 1)) ^ (ln & 7);
          const s16x4 bv = *(const s16x4*)&lV[vrow * 64 + slotv * 8 + (qd & 1) * 4];
          acc[0][dc] = mfma16(pf[t8][0], bv, acc[0][dc]);
          acc[1][dc] = mfma16(pf[t8][1], bv, acc[1][dc]);
        }
      }
      bc = bc < 2 ? bc + 1 : 0;
    }
    __syncthreads();   // all DMA drained (last iter vmcnt(0)) + reads done

    // wave-local strip row sums: lane L holds l for q row qc*16+(L&15)
    #pragma unroll
    for (int qc = 0; qc < 2; ++qc) {
      l_acc[qc] += __shfl_xor(l_acc[qc], 16);
      l_acc[qc] += __shfl_xor(l_acc[qc], 32);
    }

    // cross-strip reduce: kw=1 -> LDS -> kw=0 adds
    if (kw == 1) {
      if (lane < 16) {
        rL[qw * 32 + lane]      = l_acc[0];
        rL[qw * 32 + 16 + lane] = l_acc[1];
      }
      #pragma unroll
      for (int qc = 0; qc < 2; ++qc)
        #pragma unroll
        for (int dc = 0; dc < 4; ++dc)
          #pragma unroll
          for (int r = 0; r < 4; ++r)
            rO[(qw * 32 + qc * 16 + qd * 4 + r) * RST + dc * 16 + ln] =
                acc[qc][dc][r];
    }
    __syncthreads();
    if (kw == 0) {
      #pragma unroll
      for (int qc = 0; qc < 2; ++qc) {
        l_acc[qc] += rL[qw * 32 + qc * 16 + ln];
        #pragma unroll
        for (int dc = 0; dc < 4; ++dc)
          #pragma unroll
          for (int r = 0; r < 4; ++r)
            acc[qc][dc][r] +=
                rO[(qw * 32 + qc * 16 + qd * 4 + r) * RST + dc * 16 + ln];
      }
      if (mode == 0) {
        #pragma unroll
        for (int qc = 0; qc < 2; ++qc) {
          #pragma unroll
          for (int r = 0; r < 4; ++r) {
            const float lr  = __shfl(l_acc[qc], qd * 4 + r);
            const float inv = 1.0f / lr;
            const int q_g = q0 + qw * 32 + qc * 16 + qd * 4 + r;
            unsigned short* dst =
                ctx + ((size_t)bb * SEQLEN + q_g) * DMODEL + h * DH;
            #pragma unroll
            for (int dc = 0; dc < 4; ++dc)
              dst[dc * 16 + ln] = f2bf(acc[qc][dc][r] * inv);
          }
        }
      } else {
        float* PO = (mode == 1) ? pout1 : pout0;
        float* LO = lpart + ((mode == 1) ? (24 * 1024) : 0);
        const int qbase = q0 - 1024 + qw * 32;   // partial rows are q>=1024
        if (lane < 16) {
          LO[bh * 1024 + qbase + lane]      = l_acc[0];
          LO[bh * 1024 + qbase + 16 + lane] = l_acc[1];
        }
        #pragma unroll
        for (int qc = 0; qc < 2; ++qc)
          #pragma unroll
          for (int dc = 0; dc < 4; ++dc)
            #pragma unroll
            for (int r = 0; r < 4; ++r)
              PO[((size_t)bh * 1024 + qbase + qc * 16 + qd * 4 + r) * 64 +
                 dc * 16 + ln] = acc[qc][dc][r];
      }
    }
    __syncthreads();   // smem reusable by next run's staging
  };

  if (isA) {
    run(i * 64, 0, Ti, 0);                 // qtile i, full range, final
    run((31 - i) * 64, 0, 9 - Ti, 1);      // qtile 31-i, KV prefix, partial
  } else {
    run((31 - i) * 64, 9 - Ti, 8, 2);      // qtile 31-i, KV suffix, partial
  }
}

// ---------------------------------------------------------------------------
extern "C" void kernel_launch(void* const* d_in, const int* in_sizes, int n_in,
                              void* d_out, int out_size, void* d_ws, size_t ws_size,
                              hipStream_t stream)
{
  const float* xEnc = (const float*)d_in[0];
  const float* xDec = (const float*)d_in[1];
  const float* wQ   = (const float*)d_in[3];
  const float* bQ   = (const float*)d_in[4];
  const float* wK   = (const float*)d_in[5];
  const float* bK   = (const float*)d_in[6];
  const float* wV   = (const float*)d_in[7];
  const float* bV   = (const float*)d_in[8];
  const float* wOut = (const float*)d_in[9];
  const float* bOut = (const float*)d_in[10];

  unsigned short* ws = (unsigned short*)d_ws;
  float* pout0 = (float*)(ws + XDECB_OFF);   // dead after qkv_gemm
  float* pout1 = (float*)(ws + XENCB_OFF);   // dead after qkv_gemm
  float* lpart = (float*)(ws + WQB_OFF);     // dead after qkv_gemm

  cvt_kernel<<<dim3(512, 6), 256, 0, stream>>>(xDec, xEnc, wQ, wK, wV, wOut, ws);
  qkv_gemm<<<dim3(MTOT / 64, DMODEL / 64, 3), 256, 0, stream>>>(
      ws + XDECB_OFF, ws + XENCB_OFF, ws + WQB_OFF, ws + WKB_OFF, ws + WVB_OFF,
      bQ, bK, bV, ws + QB_OFF, ws + KB_OFF, ws + VT_OFF);
  attn_kernel<<<dim3(768), 256, 0, stream>>>(
      ws + QB_OFF, ws + KB_OFF, ws + VT_OFF, ws + CTXB_OFF,
      pout0, pout1, lpart);
  out_gemm<<<dim3(MTOT / 64, DMODEL / 64), 256, 0, stream>>>(
      ws + CTXB_OFF, ws + WOUTB_OFF, bOut, (float*)d_out,
      pout0, pout1, lpart);
}

// Round 12
// 174.954 us; speedup vs baseline: 1.0568x; 1.0568x over previous
//
#include <hip/hip_runtime.h>
#include <stdint.h>
#include <stddef.h>

#define DMODEL 768
#define NHEAD 12
#define SEQLEN 2048
#define NBATCH 2
#define DH 64
#define MTOT (NBATCH*SEQLEN)   // 4096

typedef short s16x4 __attribute__((ext_vector_type(4)));
typedef short s16x8 __attribute__((ext_vector_type(8)));
typedef float f32x4 __attribute__((ext_vector_type(4)));

// ws layout (bf16 element offsets)
#define XDECB_OFF 0u
#define XENCB_OFF 3145728u
#define WQB_OFF   6291456u
#define WKB_OFF   6881280u
#define WVB_OFF   7471104u
#define WOUTB_OFF 8060928u
#define QB_OFF    8650752u
#define KB_OFF    11796480u
#define VT_OFF    14942208u
#define CTXB_OFF  18087936u
// After qkv_gemm, the xDecB/xEncB/wQB regions are dead -> reuse as fp32
// partial-attention buffers (exact fit: 24*1024*64 f32 = 6291456 B each).
//   POUT0 = ws+XDECB_OFF  : blockB partial O   [bh][q-1024][64] f32
//   POUT1 = ws+XENCB_OFF  : blockA ph2 partial [bh][q-1024][64] f32
//   LPART = ws+WQB_OFF    : [2][bh*1024+q-1024] f32 row sums
// R12 = strict revert to the best measured configuration (R9, 177.4 us).
// Fusion attempts (R10 atomic handshake: raced; R11 out_gemm combine: -7us)
// both measured negative — separate norm_kernel is the empirical optimum.

// 0.125 * log2(e): folds the 1/sqrt(Dh) scale and exp->exp2 into Q epilogue.
#define QSCALE 0.18033688011112042f

// fp32 -> bf16, round-to-nearest-even (epilogues)
static __device__ __forceinline__ unsigned short f2bf(float f) {
  union { float f; unsigned int u; } v; v.f = f;
  unsigned int r = v.u + 0x7fffu + ((v.u >> 16) & 1u);
  return (unsigned short)(r >> 16);
}

// pack two fp32 -> bf16x2 with round-half-up: 2 adds + 1 v_perm
static __device__ __forceinline__ unsigned int pack2bf(float f0, float f1) {
  union { float f; unsigned int u; } a, b; a.f = f0; b.f = f1;
  return __builtin_amdgcn_perm(b.u + 0x8000u, a.u + 0x8000u, 0x07060302u);
}

#if __has_builtin(__builtin_amdgcn_exp2f)
#define EXP2(x) __builtin_amdgcn_exp2f(x)
#else
#define EXP2(x) exp2f(x)
#endif

static __device__ __forceinline__ f32x4 mfma16(s16x4 a, s16x4 b, f32x4 c) {
  return __builtin_amdgcn_mfma_f32_16x16x16bf16_1k(a, b, c, 0, 0, 0);
}
static __device__ __forceinline__ f32x4 mfma32(s16x8 a, s16x8 b, f32x4 c) {
  return __builtin_amdgcn_mfma_f32_16x16x32_bf16(a, b, c, 0, 0, 0);
}

// async global->LDS DMA, 16B/lane. LDS dest = wave-uniform base + lane*16.
typedef __attribute__((address_space(3))) unsigned int lds_u32_t;
typedef const __attribute__((address_space(1))) unsigned int glb_u32_t;
static __device__ __forceinline__ void gl_lds16(const unsigned short* g,
                                                unsigned short* l) {
  __builtin_amdgcn_global_load_lds((glb_u32_t*)g, (lds_u32_t*)l, 16, 0, 0);
}

// ---------------------------------------------------------------------------
// One-time fp32 -> bf16 convert of all GEMM operands. Memory-bound (~45 MB).
// ---------------------------------------------------------------------------
__global__ __launch_bounds__(256) void cvt_kernel(
    const float* __restrict__ xDec, const float* __restrict__ xEnc,
    const float* __restrict__ wQ, const float* __restrict__ wK,
    const float* __restrict__ wV, const float* __restrict__ wOut,
    unsigned short* __restrict__ ws)
{
  const int seg = blockIdx.y;
  const float* src;
  unsigned int n4, off;
  switch (seg) {
    case 0:  src = xDec; n4 = 786432; off = XDECB_OFF; break;
    case 1:  src = xEnc; n4 = 786432; off = XENCB_OFF; break;
    case 2:  src = wQ;   n4 = 147456; off = WQB_OFF;   break;
    case 3:  src = wK;   n4 = 147456; off = WKB_OFF;   break;
    case 4:  src = wV;   n4 = 147456; off = WVB_OFF;   break;
    default: src = wOut; n4 = 147456; off = WOUTB_OFF; break;
  }
  unsigned short* d = ws + off;
  const unsigned int stride = gridDim.x * blockDim.x;
  for (unsigned int i = blockIdx.x * blockDim.x + threadIdx.x; i < n4; i += stride) {
    const float4 v = ((const float4*)src)[i];
    s16x4 p;
    p[0] = (short)f2bf(v.x); p[1] = (short)f2bf(v.y);
    p[2] = (short)f2bf(v.z); p[3] = (short)f2bf(v.w);
    ((s16x4*)d)[i] = p;
  }
}

// ---------------------------------------------------------------------------
// bf16 NT GEMM, 64x64 tile, BK=64, 16x16x32 MFMA, gl_lds16 + XOR chunk
// swizzle. Counted-vmcnt 3-buffer pipeline (T4, R3-verified best).
// ---------------------------------------------------------------------------
#define BK 64
#define NKT (DMODEL / BK)   // 12

// QKV: z=0 Q=xDecB@wQ.T (+bQ)*QSCALE -> Qb[b,h,s,d]; z=1 K -> Kb; z=2 V -> Vt[b,h,d,s]
__global__ __launch_bounds__(256, 3) void qkv_gemm(
    const unsigned short* __restrict__ xDecB, const unsigned short* __restrict__ xEncB,
    const unsigned short* __restrict__ wQB, const unsigned short* __restrict__ wKB,
    const unsigned short* __restrict__ wVB,
    const float* __restrict__ bQ, const float* __restrict__ bK, const float* __restrict__ bV,
    unsigned short* __restrict__ Qb, unsigned short* __restrict__ Kb,
    unsigned short* __restrict__ Vt)
{
  const int z = blockIdx.z;
  const unsigned short* __restrict__ A = (z == 0) ? xDecB : xEncB;
  const unsigned short* __restrict__ B = (z == 0) ? wQB : ((z == 1) ? wKB : wVB);
  const float* __restrict__ bias = (z == 0) ? bQ : ((z == 1) ? bK : bV);

  __shared__ unsigned short lA[3][64 * BK];   // 3 x 8 KB, swizzled chunks
  __shared__ unsigned short lB[3][64 * BK];

  const int tid  = threadIdx.x;
  const int lane = tid & 63;
  const int wid  = tid >> 6;
  const int ln   = lane & 15;
  const int qd   = lane >> 4;
  const int m0 = blockIdx.x * 64;
  const int n0 = blockIdx.y * 64;
  const int wm = (wid & 1) * 32;
  const int wn = (wid >> 1) * 32;

  // staging: slot s = c*256 + wid*64 + lane (16B chunks); row = s>>3,
  // stored chunk = s&7, source chunk = (s&7) ^ (row&7).
  int srow[2], scol[2];
  #pragma unroll
  for (int c = 0; c < 2; ++c) {
    const int s = c * 256 + wid * 64 + lane;
    srow[c] = s >> 3;
    scol[c] = (((s & 7) ^ ((s >> 3) & 7)) * 8);
  }

  auto stage = [&](int buf, int k0) {
    #pragma unroll
    for (int c = 0; c < 2; ++c) {
      const int ldsoff = (c * 256 + wid * 64) * 8;     // shorts
      gl_lds16(A + (size_t)(m0 + srow[c]) * DMODEL + k0 + scol[c], &lA[buf][ldsoff]);
      gl_lds16(B + (size_t)(n0 + srow[c]) * DMODEL + k0 + scol[c], &lB[buf][ldsoff]);
    }
  };

  f32x4 acc[2][2] = {};

  stage(0, 0);
  stage(1, BK);            // 8 loads/lane in flight

  auto step = [&](int t, int bc, int bs) {
    if (t == NKT - 1) asm volatile("s_waitcnt vmcnt(0)" ::: "memory");
    else              asm volatile("s_waitcnt vmcnt(4)" ::: "memory");
    __builtin_amdgcn_s_barrier();
    __builtin_amdgcn_sched_barrier(0);
    if (t + 2 < NKT) stage(bs, (t + 2) * BK);
    #pragma unroll
    for (int kc = 0; kc < 2; ++kc) {
      s16x8 af[2], bfr[2];
      #pragma unroll
      for (int i = 0; i < 2; ++i) {
        const int r = wm + i * 16 + ln;
        af[i] = *(const s16x8*)&lA[bc][r * 64 + (((kc * 4 + qd) ^ (r & 7)) * 8)];
      }
      #pragma unroll
      for (int j = 0; j < 2; ++j) {
        const int r = wn + j * 16 + ln;
        bfr[j] = *(const s16x8*)&lB[bc][r * 64 + (((kc * 4 + qd) ^ (r & 7)) * 8)];
      }
      #pragma unroll
      for (int i = 0; i < 2; ++i)
        #pragma unroll
        for (int j = 0; j < 2; ++j)
          acc[i][j] = mfma32(af[i], bfr[j], acc[i][j]);
    }
  };

  for (int tb = 0; tb < NKT; tb += 3) {   // NKT % 3 == 0: bufs fold statically
    step(tb + 0, 0, 2);
    step(tb + 1, 1, 0);
    step(tb + 2, 2, 1);
  }

  // C/D layout: col = ln, row = qd*4 + r
  #pragma unroll
  for (int j = 0; j < 2; ++j) {
    const int n_g = n0 + wn + j * 16 + ln;
    const float bv = bias[n_g];
    const int h    = n_g >> 6;
    const int dcol = n_g & 63;
    #pragma unroll
    for (int i = 0; i < 2; ++i) {
      #pragma unroll
      for (int r = 0; r < 4; ++r) {
        const int m_g  = m0 + wm + i * 16 + qd * 4 + r;
        const int bb   = m_g >> 11;
        const int srow2 = m_g & 2047;
        const float val = acc[i][j][r] + bv;
        if (z == 0)
          Qb[((size_t)((bb * NHEAD + h) * SEQLEN + srow2)) * DH + dcol] = f2bf(val * QSCALE);
        else if (z == 1)
          Kb[((size_t)((bb * NHEAD + h) * SEQLEN + srow2)) * DH + dcol] = f2bf(val);
        else
          Vt[((size_t)((bb * NHEAD + h) * DH + dcol)) * SEQLEN + srow2] = f2bf(val);
      }
    }
  }
}

__global__ __launch_bounds__(256, 3) void out_gemm(
    const unsigned short* __restrict__ ctx, const unsigned short* __restrict__ wOutB,
    const float* __restrict__ bOut, float* __restrict__ out)
{
  __shared__ unsigned short lA[3][64 * BK];
  __shared__ unsigned short lB[3][64 * BK];

  const int tid  = threadIdx.x;
  const int lane = tid & 63;
  const int wid  = tid >> 6;
  const int ln   = lane & 15;
  const int qd   = lane >> 4;
  const int m0 = blockIdx.x * 64;
  const int n0 = blockIdx.y * 64;
  const int wm = (wid & 1) * 32;
  const int wn = (wid >> 1) * 32;

  int srow[2], scol[2];
  #pragma unroll
  for (int c = 0; c < 2; ++c) {
    const int s = c * 256 + wid * 64 + lane;
    srow[c] = s >> 3;
    scol[c] = (((s & 7) ^ ((s >> 3) & 7)) * 8);
  }

  auto stage = [&](int buf, int k0) {
    #pragma unroll
    for (int c = 0; c < 2; ++c) {
      const int ldsoff = (c * 256 + wid * 64) * 8;
      gl_lds16(ctx + (size_t)(m0 + srow[c]) * DMODEL + k0 + scol[c], &lA[buf][ldsoff]);
      gl_lds16(wOutB + (size_t)(n0 + srow[c]) * DMODEL + k0 + scol[c], &lB[buf][ldsoff]);
    }
  };

  f32x4 acc[2][2] = {};

  stage(0, 0);
  stage(1, BK);

  auto step = [&](int t, int bc, int bs) {
    if (t == NKT - 1) asm volatile("s_waitcnt vmcnt(0)" ::: "memory");
    else              asm volatile("s_waitcnt vmcnt(4)" ::: "memory");
    __builtin_amdgcn_s_barrier();
    __builtin_amdgcn_sched_barrier(0);
    if (t + 2 < NKT) stage(bs, (t + 2) * BK);
    #pragma unroll
    for (int kc = 0; kc < 2; ++kc) {
      s16x8 af[2], bfr[2];
      #pragma unroll
      for (int i = 0; i < 2; ++i) {
        const int r = wm + i * 16 + ln;
        af[i] = *(const s16x8*)&lA[bc][r * 64 + (((kc * 4 + qd) ^ (r & 7)) * 8)];
      }
      #pragma unroll
      for (int j = 0; j < 2; ++j) {
        const int r = wn + j * 16 + ln;
        bfr[j] = *(const s16x8*)&lB[bc][r * 64 + (((kc * 4 + qd) ^ (r & 7)) * 8)];
      }
      #pragma unroll
      for (int i = 0; i < 2; ++i)
        #pragma unroll
        for (int j = 0; j < 2; ++j)
          acc[i][j] = mfma32(af[i], bfr[j], acc[i][j]);
    }
  };

  for (int tb = 0; tb < NKT; tb += 3) {
    step(tb + 0, 0, 2);
    step(tb + 1, 1, 0);
    step(tb + 2, 2, 1);
  }

  #pragma unroll
  for (int j = 0; j < 2; ++j) {
    const int n_g = n0 + wn + j * 16 + ln;
    const float bv = bOut[n_g];
    #pragma unroll
    for (int i = 0; i < 2; ++i) {
      #pragma unroll
      for (int r = 0; r < 4; ++r) {
        const int m_g = m0 + wm + i * 16 + qd * 4 + r;
        out[(size_t)m_g * DMODEL + n_g] = acc[i][j][r] + bv;
      }
    }
  }
}

// ---------------------------------------------------------------------------
// Flash attention, FIXED-BASE softmax — counted-vmcnt 3-buffer pipeline
// (KVT=64, 3 blocks/CU), 2x2 wave split, conflict-free gl_lds16 staging,
// XCD-local remap, R8 load-balanced pairing. R9-verified best (~30 us).
// ---------------------------------------------------------------------------
#define KVT 64
#define VOFF 4096   // shorts: V tile offset inside one buffer
#define RST 68      // epilogue fp32 row stride (64+4)

__global__ __launch_bounds__(256, 3) void attn_kernel(
    const unsigned short* __restrict__ Qb, const unsigned short* __restrict__ Kb,
    const unsigned short* __restrict__ Vt, unsigned short* __restrict__ ctx,
    float* __restrict__ pout0, float* __restrict__ pout1,
    float* __restrict__ lpart)
{
  // [buf][ lK 4096 shorts | lV 4096 shorts ] = 3 x 16 KB = 48 KB
  __shared__ __attribute__((aligned(16))) unsigned short smem[3][8192];

  const int tid  = threadIdx.x;
  const int lane = tid & 63;
  const int wid  = tid >> 6;
  const int ln   = lane & 15;
  const int qd   = lane >> 4;
  const int qw   = wid & 1;    // q-half owner
  const int kw   = wid >> 1;   // kv-strip owner (32 rows)

  // XCD-local remap: all blocks of a head on one XCD (L2-resident KV)
  const int ord  = blockIdx.x;          // 0..767
  const int xcd  = ord & 7;
  const int slot = ord >> 3;            // 0..95
  const int bh   = xcd * 3 + (slot >> 5);
  const int p    = slot & 31;           // 0..31

  const bool isA = p < 16;
  const int i  = isA ? p : (p - 16);    // pair index 0..15
  const int Ti = (i + 2) >> 1;          // ceil((i+1)/2): KVT128-units of qtile i

  const unsigned short* Kbase = Kb + (size_t)bh * SEQLEN * DH;
  const unsigned short* Vbase = Vt + (size_t)bh * DH * SEQLEN;
  const int bb = bh / NHEAD;
  const int h  = bh % NHEAD;

  float* rO = (float*)&smem[0][0];      // 64 x RST f32 (aliases buf0+buf1)
  float* rL = rO + 64 * RST;

  // DMA stage (4 loads/lane): K tile [64][64], V tile [64][64]; chunk f:
  // row=f>>3, slot=f&7, stored content = source chunk slot^(row&7).
  auto stage = [&](int b, int kv0) {
    #pragma unroll
    for (int c = 0; c < 2; ++c) {
      const int f = tid + c * 256;   // 0..511
      const int row = f >> 3, sl = f & 7;
      gl_lds16(Kbase + (size_t)(kv0 + row) * DH + ((sl ^ (row & 7)) * 8),
               &smem[b][f * 8]);
    }
    #pragma unroll
    for (int c = 0; c < 2; ++c) {
      const int f = tid + c * 256;
      const int row = f >> 3, sl = f & 7;
      gl_lds16(Vbase + (size_t)row * SEQLEN + kv0 + ((sl ^ (row & 7)) * 8),
               &smem[b][VOFF + f * 8]);
    }
  };

  // mode 0: final (normalize + bf16 ctx write); 1: partial->slot1; 2: ->slot0
  // T0/NT in KVT128 units (kv range [T0*128, (T0+NT)*128)).
  auto run = [&](int q0, int T0, int NT, int mode) {
    const int t0 = T0 * 2, tend = (T0 + NT) * 2;   // KVT64 tiles; tend-t0 >= 2

    // Q fragments: this wave's 32 q rows (B-operand layout)
    s16x8 Qf[2][2];
    #pragma unroll
    for (int qc = 0; qc < 2; ++qc)
      #pragma unroll
      for (int kc = 0; kc < 2; ++kc)
        Qf[qc][kc] = *(const s16x8*)(Qb +
            ((size_t)bh * SEQLEN + q0 + qw * 32 + qc * 16 + ln) * DH + kc * 32 + qd * 8);

    float l_acc[2] = {};
    f32x4 acc[2][4] = {};   // [qc][dc]: O[q0+qw*32+qc*16+qd*4+r][dc*16+ln]

    stage(0, t0 * KVT);
    stage(1, (t0 + 1) * KVT);
    int bc = 0;
    for (int t = t0; t < tend; ++t) {
      if (t + 1 < tend) asm volatile("s_waitcnt vmcnt(4)" ::: "memory");
      else              asm volatile("s_waitcnt vmcnt(0)" ::: "memory");
      __builtin_amdgcn_s_barrier();
      __builtin_amdgcn_sched_barrier(0);
      if (t + 2 < tend) stage(bc >= 1 ? bc - 1 : bc + 2, (t + 2) * KVT);

      const unsigned short* lK = &smem[bc][0];
      const unsigned short* lV = &smem[bc][VOFF];
      const int kv0 = t * KVT;
      const bool diag = (kv0 + KVT > q0);   // 64-aligned ranges: one diag tile

      // S^T strips: kv = kv0 + kw*32 + t8*16 + qd*4 + r, q = q0+qw*32+qc*16+ln
      s16x4 pf[2][2];
      #pragma unroll
      for (int t8 = 0; t8 < 2; ++t8) {
        const int row = kw * 32 + t8 * 16 + ln;      // row&7 == ln&7
        const s16x8 k0 = *(const s16x8*)&lK[row * 64 + ((qd ^ (ln & 7)) * 8)];
        const s16x8 k1 = *(const s16x8*)&lK[row * 64 + (((4 + qd) ^ (ln & 7)) * 8)];
        f32x4 sq[2] = {};
        sq[0] = mfma32(k0, Qf[0][0], sq[0]);
        sq[0] = mfma32(k1, Qf[0][1], sq[0]);
        sq[1] = mfma32(k0, Qf[1][0], sq[1]);
        sq[1] = mfma32(k1, Qf[1][1], sq[1]);
        #pragma unroll
        for (int qc = 0; qc < 2; ++qc) {
          if (diag) {
            #pragma unroll
            for (int r = 0; r < 4; ++r) {
              const int kv = kv0 + kw * 32 + t8 * 16 + qd * 4 + r;
              const int q  = q0 + qw * 32 + qc * 16 + ln;
              sq[qc][r] = (kv > q) ? -1e30f : sq[qc][r];
            }
          }
          const float p0 = EXP2(sq[qc][0]);
          const float p1 = EXP2(sq[qc][1]);
          const float p2 = EXP2(sq[qc][2]);
          const float p3 = EXP2(sq[qc][3]);
          l_acc[qc] += (p0 + p1) + (p2 + p3);
          union { unsigned int u[2]; s16x4 v; } pk;
          pk.u[0] = pack2bf(p0, p1);
          pk.u[1] = pack2bf(p2, p3);
          pf[t8][qc] = pk.v;
        }
      }

      // O += P @ V over this wave's 32-kv strip
      #pragma unroll
      for (int t8 = 0; t8 < 2; ++t8) {
        #pragma unroll
        for (int dc = 0; dc < 4; ++dc) {
          const int vrow  = dc * 16 + ln;            // row&7 == ln&7
          const int slotv = (kw * 4 + t8 * 2 + (qd >> 1)) ^ (ln & 7);
          const s16x4 bv = *(const s16x4*)&lV[vrow * 64 + slotv * 8 + (qd & 1) * 4];
          acc[0][dc] = mfma16(pf[t8][0], bv, acc[0][dc]);
          acc[1][dc] = mfma16(pf[t8][1], bv, acc[1][dc]);
        }
      }
      bc = bc < 2 ? bc + 1 : 0;
    }
    __syncthreads();   // all DMA drained (last iter vmcnt(0)) + reads done

    // wave-local strip row sums: lane L holds l for q row qc*16+(L&15)
    #pragma unroll
    for (int qc = 0; qc < 2; ++qc) {
      l_acc[qc] += __shfl_xor(l_acc[qc], 16);
      l_acc[qc] += __shfl_xor(l_acc[qc], 32);
    }

    // cross-strip reduce: kw=1 -> LDS -> kw=0 adds
    if (kw == 1) {
      if (lane < 16) {
        rL[qw * 32 + lane]      = l_acc[0];
        rL[qw * 32 + 16 + lane] = l_acc[1];
      }
      #pragma unroll
      for (int qc = 0; qc < 2; ++qc)
        #pragma unroll
        for (int dc = 0; dc < 4; ++dc)
          #pragma unroll
          for (int r = 0; r < 4; ++r)
            rO[(qw * 32 + qc * 16 + qd * 4 + r) * RST + dc * 16 + ln] =
                acc[qc][dc][r];
    }
    __syncthreads();
    if (kw == 0) {
      #pragma unroll
      for (int qc = 0; qc < 2; ++qc) {
        l_acc[qc] += rL[qw * 32 + qc * 16 + ln];
        #pragma unroll
        for (int dc = 0; dc < 4; ++dc)
          #pragma unroll
          for (int r = 0; r < 4; ++r)
            acc[qc][dc][r] +=
                rO[(qw * 32 + qc * 16 + qd * 4 + r) * RST + dc * 16 + ln];
      }
      if (mode == 0) {
        #pragma unroll
        for (int qc = 0; qc < 2; ++qc) {
          #pragma unroll
          for (int r = 0; r < 4; ++r) {
            const float lr  = __shfl(l_acc[qc], qd * 4 + r);
            const float inv = 1.0f / lr;
            const int q_g = q0 + qw * 32 + qc * 16 + qd * 4 + r;
            unsigned short* dst =
                ctx + ((size_t)bb * SEQLEN + q_g) * DMODEL + h * DH;
            #pragma unroll
            for (int dc = 0; dc < 4; ++dc)
              dst[dc * 16 + ln] = f2bf(acc[qc][dc][r] * inv);
          }
        }
      } else {
        float* PO = (mode == 1) ? pout1 : pout0;
        float* LO = lpart + ((mode == 1) ? (24 * 1024) : 0);
        const int qbase = q0 - 1024 + qw * 32;   // partial rows are q>=1024
        if (lane < 16) {
          LO[bh * 1024 + qbase + lane]      = l_acc[0];
          LO[bh * 1024 + qbase + 16 + lane] = l_acc[1];
        }
        #pragma unroll
        for (int qc = 0; qc < 2; ++qc)
          #pragma unroll
          for (int dc = 0; dc < 4; ++dc)
            #pragma unroll
            for (int r = 0; r < 4; ++r)
              PO[((size_t)bh * 1024 + qbase + qc * 16 + qd * 4 + r) * 64 +
                 dc * 16 + ln] = acc[qc][dc][r];
      }
    }
    __syncthreads();   // smem reusable by next run's staging
  };

  if (isA) {
    run(i * 64, 0, Ti, 0);                 // qtile i, full range, final
    run((31 - i) * 64, 0, 9 - Ti, 1);      // qtile 31-i, KV prefix, partial
  } else {
    run((31 - i) * 64, 9 - Ti, 8, 2);      // qtile 31-i, KV suffix, partial
  }
}

// ---------------------------------------------------------------------------
// Combine the two fp32 partial slots and normalize rows q>=1024.
// 1,572,864 elements; one float4 per thread; grid 1536x256.
// ---------------------------------------------------------------------------
__global__ __launch_bounds__(256) void norm_kernel(
    const float* __restrict__ pout0, const float* __restrict__ pout1,
    const float* __restrict__ lpart, unsigned short* __restrict__ ctx)
{
  const int e4  = blockIdx.x * 256 + threadIdx.x;  // float4 index
  const int d4  = e4 & 15;                         // 16 float4 per 64-wide row
  const int row = e4 >> 4;                         // bh*1024 + (q-1024)
  const int bh  = row >> 10;
  const int qr  = row & 1023;
  const float l = lpart[row] + lpart[24 * 1024 + row];
  const float inv = 1.0f / l;
  const float4 a = ((const float4*)pout0)[e4];
  const float4 b = ((const float4*)pout1)[e4];
  const int bb = bh / NHEAD;
  const int h  = bh % NHEAD;
  unsigned short* dst =
      ctx + ((size_t)bb * SEQLEN + 1024 + qr) * DMODEL + h * DH + d4 * 4;
  s16x4 o;
  o[0] = (short)f2bf((a.x + b.x) * inv);
  o[1] = (short)f2bf((a.y + b.y) * inv);
  o[2] = (short)f2bf((a.z + b.z) * inv);
  o[3] = (short)f2bf((a.w + b.w) * inv);
  *(s16x4*)dst = o;
}

// ---------------------------------------------------------------------------
extern "C" void kernel_launch(void* const* d_in, const int* in_sizes, int n_in,
                              void* d_out, int out_size, void* d_ws, size_t ws_size,
                              hipStream_t stream)
{
  const float* xEnc = (const float*)d_in[0];
  const float* xDec = (const float*)d_in[1];
  const float* wQ   = (const float*)d_in[3];
  const float* bQ   = (const float*)d_in[4];
  const float* wK   = (const float*)d_in[5];
  const float* bK   = (const float*)d_in[6];
  const float* wV   = (const float*)d_in[7];
  const float* bV   = (const float*)d_in[8];
  const float* wOut = (const float*)d_in[9];
  const float* bOut = (const float*)d_in[10];

  unsigned short* ws = (unsigned short*)d_ws;
  float* pout0 = (float*)(ws + XDECB_OFF);   // dead after qkv_gemm
  float* pout1 = (float*)(ws + XENCB_OFF);   // dead after qkv_gemm
  float* lpart = (float*)(ws + WQB_OFF);     // dead after qkv_gemm

  cvt_kernel<<<dim3(512, 6), 256, 0, stream>>>(xDec, xEnc, wQ, wK, wV, wOut, ws);
  qkv_gemm<<<dim3(MTOT / 64, DMODEL / 64, 3), 256, 0, stream>>>(
      ws + XDECB_OFF, ws + XENCB_OFF, ws + WQB_OFF, ws + WKB_OFF, ws + WVB_OFF,
      bQ, bK, bV, ws + QB_OFF, ws + KB_OFF, ws + VT_OFF);
  attn_kernel<<<dim3(768), 256, 0, stream>>>(
      ws + QB_OFF, ws + KB_OFF, ws + VT_OFF, ws + CTXB_OFF,
      pout0, pout1, lpart);
  norm_kernel<<<dim3((24 * 1024 * 16) / 256), 256, 0, stream>>>(
      pout0, pout1, lpart, ws + CTXB_OFF);
  out_gemm<<<dim3(MTOT / 64, DMODEL / 64), 256, 0, stream>>>(
      ws + CTXB_OFF, ws + WOUTB_OFF, bOut, (float*)d_out);
}